// Round 1
// baseline (438.837 us; speedup 1.0000x reference)
//
#include <hip/hip_runtime.h>
#include <math.h>

// GCN 2-layer: out = log_softmax( GCN2( relu( GCN1(x) ) ) )
// GCNConv: out = D^-1/2 A D^-1/2 (X W) + (X W)/deg + b,  deg = 1 + indeg(dst)
//
// Strategy: build padded CSR by dst (CAP=64 slots/node, Poisson(16) => overflow ~0),
// then aggregation = pure gather, one wave per node, lane = feature.

#define CAP 64

// ---------------- CSR build ----------------

__global__ __launch_bounds__(256) void build_csr(const int* __restrict__ src,
                                                 const int* __restrict__ dst,
                                                 int* __restrict__ cnt,
                                                 int* __restrict__ csr_src, int E) {
    int e = blockIdx.x * 256 + threadIdx.x;
    if (e >= E) return;
    int s = src[e], d = dst[e];
    int slot = atomicAdd(&cnt[d], 1);
    if (slot < CAP) csr_src[d * CAP + slot] = s;
}

__global__ __launch_bounds__(256) void compute_dinv(const int* __restrict__ cnt,
                                                    float* __restrict__ dinv, int N) {
    int v = blockIdx.x * 256 + threadIdx.x;
    if (v < N) dinv[v] = rsqrtf((float)cnt[v] + 1.0f);
}

__global__ __launch_bounds__(256) void fill_norm(const int* __restrict__ cnt,
                                                 const int* __restrict__ csr_src,
                                                 const float* __restrict__ dinv,
                                                 float* __restrict__ csr_norm, int N) {
    int t = blockIdx.x * 256 + threadIdx.x;
    int v = t >> 6, j = t & 63;          // wave-uniform v
    if (v >= N) return;
    int c = cnt[v]; if (c > CAP) c = CAP;
    if (j < c) {
        int s = csr_src[v * CAP + j];
        csr_norm[v * CAP + j] = dinv[s] * dinv[v];
    }
}

// ---------------- tiled fp32 GEMM: OUT[N,OUTC] = X[N,K] @ W[K,OUTC] ----------------
// 64 rows/block, W zero-padded to 64 cols in LDS, 4x4 register blocking, b128 LDS ops.

template <int K, int OUTC>
__global__ __launch_bounds__(256) void gemm_tiled(const float* __restrict__ X,
                                                  const float* __restrict__ W,
                                                  float* __restrict__ OUT, int N) {
    constexpr int KP = K + 4;            // pad rows for bank spread, keeps 16B align
    __shared__ float xs[64 * KP];
    __shared__ float Wp[K * 64];
    const int t = threadIdx.x;
    const int row0 = blockIdx.x * 64;

    for (int i = t; i < K * 64; i += 256) {
        int k = i >> 6, c = i & 63;
        Wp[i] = (c < OUTC) ? W[k * OUTC + c] : 0.f;
    }
    constexpr int KQ = K / 4;
    const float4* X4 = reinterpret_cast<const float4*>(X);
    for (int i = t; i < 64 * KQ; i += 256) {
        int r = i / KQ, kq = i - r * KQ;
        int m = row0 + r;
        float4 v = make_float4(0.f, 0.f, 0.f, 0.f);
        if (m < N) v = X4[(size_t)m * KQ + kq];
        *reinterpret_cast<float4*>(&xs[r * KP + kq * 4]) = v;
    }
    __syncthreads();

    const int c4 = (t & 15) * 4;         // col quad
    const int r4 = (t >> 4) * 4;         // row quad
    float acc[4][4] = {};
    for (int k = 0; k < K; k += 4) {
        float4 A[4], B[4];
        #pragma unroll
        for (int i = 0; i < 4; i++)
            A[i] = *reinterpret_cast<const float4*>(&xs[(r4 + i) * KP + k]);
        #pragma unroll
        for (int kk = 0; kk < 4; kk++)
            B[kk] = *reinterpret_cast<const float4*>(&Wp[(k + kk) * 64 + c4]);
        const float* Af = reinterpret_cast<const float*>(A);
        const float* Bf = reinterpret_cast<const float*>(B);
        #pragma unroll
        for (int i = 0; i < 4; i++)
            #pragma unroll
            for (int kk = 0; kk < 4; kk++) {
                float av = Af[i * 4 + kk];
                #pragma unroll
                for (int j = 0; j < 4; j++)
                    acc[i][j] = fmaf(av, Bf[kk * 4 + j], acc[i][j]);
            }
    }
    #pragma unroll
    for (int i = 0; i < 4; i++) {
        int m = row0 + r4 + i;
        if (m >= N) continue;
        #pragma unroll
        for (int j = 0; j < 4; j++) {
            int c = c4 + j;
            if (c < OUTC) OUT[(size_t)m * OUTC + c] = acc[i][j];
        }
    }
}

// ---------------- layer-1 aggregation: h = relu(agg + xw/deg + b1), F=64 ----------------
// one wave per node, lane = feature

__global__ __launch_bounds__(256) void agg1_relu(const float* __restrict__ xw,
                                                 const int* __restrict__ csr_src,
                                                 const float* __restrict__ csr_norm,
                                                 const int* __restrict__ cnt,
                                                 const float* __restrict__ dinv,
                                                 const float* __restrict__ bias,
                                                 float* __restrict__ h, int N) {
    int wid = (blockIdx.x * 256 + threadIdx.x) >> 6;
    int f = threadIdx.x & 63;
    if (wid >= N) return;
    int v = wid;
    int c = cnt[v]; if (c > CAP) c = CAP;
    int base = v * CAP;
    int sl = (f < c) ? csr_src[base + f] : 0;
    float wl = (f < c) ? csr_norm[base + f] : 0.f;
    float acc = 0.f;
    int j = 0;
    for (; j + 4 <= c; j += 4) {
        int s0 = __shfl(sl, j), s1 = __shfl(sl, j + 1);
        int s2 = __shfl(sl, j + 2), s3 = __shfl(sl, j + 3);
        float w0 = __shfl(wl, j), w1 = __shfl(wl, j + 1);
        float w2 = __shfl(wl, j + 2), w3 = __shfl(wl, j + 3);
        float x0 = xw[(size_t)s0 * 64 + f];
        float x1 = xw[(size_t)s1 * 64 + f];
        float x2 = xw[(size_t)s2 * 64 + f];
        float x3 = xw[(size_t)s3 * 64 + f];
        acc = fmaf(x0, w0, acc);
        acc = fmaf(x1, w1, acc);
        acc = fmaf(x2, w2, acc);
        acc = fmaf(x3, w3, acc);
    }
    for (; j < c; j++) {
        int s = __shfl(sl, j);
        float w = __shfl(wl, j);
        acc = fmaf(xw[(size_t)s * 64 + f], w, acc);
    }
    float di = dinv[v];
    acc = fmaf(xw[(size_t)v * 64 + f], di * di, acc);
    acc += bias[f];
    h[(size_t)v * 64 + f] = fmaxf(acc, 0.f);
}

// ---------------- layer-2 aggregation fused with log_softmax, F=47 ----------------

__global__ __launch_bounds__(256) void agg2_lsm(const float* __restrict__ hw,
                                                const int* __restrict__ csr_src,
                                                const float* __restrict__ csr_norm,
                                                const int* __restrict__ cnt,
                                                const float* __restrict__ dinv,
                                                const float* __restrict__ bias,
                                                float* __restrict__ out, int N) {
    int wid = (blockIdx.x * 256 + threadIdx.x) >> 6;
    int f = threadIdx.x & 63;
    if (wid >= N) return;
    int v = wid;
    int c = cnt[v]; if (c > CAP) c = CAP;
    int base = v * CAP;
    int sl = (f < c) ? csr_src[base + f] : 0;
    float wl = (f < c) ? csr_norm[base + f] : 0.f;
    const bool act = (f < 47);
    float acc = 0.f;
    int j = 0;
    for (; j + 4 <= c; j += 4) {
        int s0 = __shfl(sl, j), s1 = __shfl(sl, j + 1);
        int s2 = __shfl(sl, j + 2), s3 = __shfl(sl, j + 3);
        float w0 = __shfl(wl, j), w1 = __shfl(wl, j + 1);
        float w2 = __shfl(wl, j + 2), w3 = __shfl(wl, j + 3);
        if (act) {
            float x0 = hw[(size_t)s0 * 47 + f];
            float x1 = hw[(size_t)s1 * 47 + f];
            float x2 = hw[(size_t)s2 * 47 + f];
            float x3 = hw[(size_t)s3 * 47 + f];
            acc = fmaf(x0, w0, acc);
            acc = fmaf(x1, w1, acc);
            acc = fmaf(x2, w2, acc);
            acc = fmaf(x3, w3, acc);
        }
    }
    for (; j < c; j++) {
        int s = __shfl(sl, j);
        float w = __shfl(wl, j);
        if (act) acc = fmaf(hw[(size_t)s * 47 + f], w, acc);
    }
    float di = dinv[v];
    float val;
    if (act) {
        acc = fmaf(hw[(size_t)v * 47 + f], di * di, acc);
        acc += bias[f];
        val = acc;
    } else {
        val = -INFINITY;
    }
    // wave-wide max over 64 lanes (lanes >=47 contribute -inf)
    float m = val;
    #pragma unroll
    for (int mask = 1; mask < 64; mask <<= 1)
        m = fmaxf(m, __shfl_xor(m, mask));
    float e = act ? __expf(val - m) : 0.f;
    float ssum = e;
    #pragma unroll
    for (int mask = 1; mask < 64; mask <<= 1)
        ssum += __shfl_xor(ssum, mask);
    if (act) out[(size_t)v * 47 + f] = val - m - __logf(ssum);
}

// ---------------- launch ----------------

extern "C" void kernel_launch(void* const* d_in, const int* in_sizes, int n_in,
                              void* d_out, int out_size, void* d_ws, size_t ws_size,
                              hipStream_t stream) {
    const float* x  = (const float*)d_in[0];
    const int*   ei = (const int*)d_in[1];
    const float* W1 = (const float*)d_in[2];
    const float* b1 = (const float*)d_in[3];
    const float* W2 = (const float*)d_in[4];
    const float* b2 = (const float*)d_in[5];
    float* out = (float*)d_out;

    const int N = in_sizes[0] / 128;
    const int E = in_sizes[1] / 2;
    const int* src = ei;
    const int* dst = ei + E;

    char* ws = (char*)d_ws;
    size_t off = 0;
    auto alloc = [&](size_t bytes) {
        void* p = ws + off;
        off += (bytes + 255) & ~(size_t)255;
        return p;
    };
    int*   cnt      = (int*)  alloc((size_t)N * 4);
    float* dinv     = (float*)alloc((size_t)N * 4);
    int*   csr_src  = (int*)  alloc((size_t)N * CAP * 4);
    float* csr_norm = (float*)alloc((size_t)N * CAP * 4);
    float* buf1     = (float*)alloc((size_t)N * 64 * 4);  // xw1, later hw2
    float* buf2     = (float*)alloc((size_t)N * 64 * 4);  // h

    hipMemsetAsync(cnt, 0, (size_t)N * 4, stream);
    build_csr<<<(E + 255) / 256, 256, 0, stream>>>(src, dst, cnt, csr_src, E);
    compute_dinv<<<(N + 255) / 256, 256, 0, stream>>>(cnt, dinv, N);
    fill_norm<<<(N * 64 + 255) / 256, 256, 0, stream>>>(cnt, csr_src, dinv, csr_norm, N);

    gemm_tiled<128, 64><<<(N + 63) / 64, 256, 0, stream>>>(x, W1, buf1, N);
    agg1_relu<<<(N + 3) / 4, 256, 0, stream>>>(buf1, csr_src, csr_norm, cnt, dinv, b1, buf2, N);
    gemm_tiled<64, 47><<<(N + 63) / 64, 256, 0, stream>>>(buf2, W2, buf1, N);
    agg2_lsm<<<(N + 3) / 4, 256, 0, stream>>>(buf1, csr_src, csr_norm, cnt, dinv, b2, out, N);
}

// Round 3
// 380.918 us; speedup vs baseline: 1.1521x; 1.1521x over previous
//
#include <hip/hip_runtime.h>
#include <hip/hip_bf16.h>
#include <math.h>

// GCN 2-layer: out = log_softmax( GCN2( relu( GCN1(x) ) ) )
// GCNConv: out = D^-1/2 A D^-1/2 (X W) + (X W)/deg + b,  deg = 1 + indeg(dst)
//
// Round 2 (resubmit — round-2 bench hit GPUAcquisitionTimeout, no data):
// (1) XCD-partitioned CSR build (kills the 96MB scattered-write amplification
// seen in round-1 rocprof), (2) bf16 gather buffers (halves the E*row gather
// traffic), (3) per-edge norm computed from L2-resident dinv[] instead of a
// materialized csr_norm stream.

#define CAP 64
typedef unsigned short u16;

__device__ __forceinline__ u16 f2bf(float f) {
    __hip_bfloat16 h = __float2bfloat16(f);
    return *reinterpret_cast<u16*>(&h);
}
__device__ __forceinline__ float bf2f(u16 u) {
    return __uint_as_float(((unsigned)u) << 16);
}

// ---------------- CSR build, dst-range partitioned (8 groups ~ 8 XCDs) ----------------
// Group g = blockIdx%8 owns nodes [g*chunk, (g+1)*chunk). Each group scans the
// whole edge list (slice-strided across its blocks); scatter writes stay in a
// 3.2MB slice that fits one XCD's L2.

__global__ __launch_bounds__(256) void build_csr(const int* __restrict__ src,
                                                 const int* __restrict__ dst,
                                                 int* __restrict__ cnt,
                                                 int* __restrict__ csr_src,
                                                 int E, int chunk) {
    const int g = blockIdx.x & 7;
    const int slice = blockIdx.x >> 3;
    const int nsl = gridDim.x >> 3;
    const int lo = g * chunk, hi = lo + chunk;
    for (int e = slice * 256 + threadIdx.x; e < E; e += nsl * 256) {
        int d = dst[e];
        if (d >= lo && d < hi) {
            int slot = atomicAdd(&cnt[d], 1);
            if (slot < CAP) csr_src[d * CAP + slot] = src[e];
        }
    }
}

__global__ __launch_bounds__(256) void compute_dinv(const int* __restrict__ cnt,
                                                    float* __restrict__ dinv, int N) {
    int v = blockIdx.x * 256 + threadIdx.x;
    if (v < N) dinv[v] = rsqrtf((float)cnt[v] + 1.0f);
}

// ---------------- tiled fp32 GEMM -> bf16 out: OUT[N,OSTR] = X[N,K] @ W[K,OUTC] ----------------
// 64 rows/block, W zero-padded to 64 cols in LDS, 4x4 register blocking.

template <int K, int OUTC, int OSTR>
__global__ __launch_bounds__(256) void gemm_tiled(const float* __restrict__ X,
                                                  const float* __restrict__ W,
                                                  u16* __restrict__ OUT, int N) {
    constexpr int KP = K + 4;
    __shared__ float xs[64 * KP];
    __shared__ float Wp[K * 64];
    const int t = threadIdx.x;
    const int row0 = blockIdx.x * 64;

    for (int i = t; i < K * 64; i += 256) {
        int k = i >> 6, c = i & 63;
        Wp[i] = (c < OUTC) ? W[k * OUTC + c] : 0.f;
    }
    constexpr int KQ = K / 4;
    const float4* X4 = reinterpret_cast<const float4*>(X);
    for (int i = t; i < 64 * KQ; i += 256) {
        int r = i / KQ, kq = i - r * KQ;
        int m = row0 + r;
        float4 v = make_float4(0.f, 0.f, 0.f, 0.f);
        if (m < N) v = X4[(size_t)m * KQ + kq];
        *reinterpret_cast<float4*>(&xs[r * KP + kq * 4]) = v;
    }
    __syncthreads();

    const int c4 = (t & 15) * 4;
    const int r4 = (t >> 4) * 4;
    float acc[4][4] = {};
    for (int k = 0; k < K; k += 4) {
        float4 A[4], B[4];
        #pragma unroll
        for (int i = 0; i < 4; i++)
            A[i] = *reinterpret_cast<const float4*>(&xs[(r4 + i) * KP + k]);
        #pragma unroll
        for (int kk = 0; kk < 4; kk++)
            B[kk] = *reinterpret_cast<const float4*>(&Wp[(k + kk) * 64 + c4]);
        const float* Af = reinterpret_cast<const float*>(A);
        const float* Bf = reinterpret_cast<const float*>(B);
        #pragma unroll
        for (int i = 0; i < 4; i++)
            #pragma unroll
            for (int kk = 0; kk < 4; kk++) {
                float av = Af[i * 4 + kk];
                #pragma unroll
                for (int j = 0; j < 4; j++)
                    acc[i][j] = fmaf(av, Bf[kk * 4 + j], acc[i][j]);
            }
    }
    if (c4 >= OSTR) return;   // cols beyond buffer stride don't exist
    #pragma unroll
    for (int i = 0; i < 4; i++) {
        int m = row0 + r4 + i;
        if (m >= N) continue;
        ushort4 o;
        o.x = f2bf(acc[i][0]); o.y = f2bf(acc[i][1]);
        o.z = f2bf(acc[i][2]); o.w = f2bf(acc[i][3]);
        *reinterpret_cast<ushort4*>(&OUT[(size_t)m * OSTR + c4]) = o;
    }
}

// ---------------- layer-1 aggregation: h = relu(agg + xw/deg + b1), F=64 ----------------
// one wave per node, lane = feature; xw gathered as bf16, accumulated fp32.

__global__ __launch_bounds__(256) void agg1_relu(const u16* __restrict__ xw,
                                                 const int* __restrict__ csr_src,
                                                 const int* __restrict__ cnt,
                                                 const float* __restrict__ dinv,
                                                 const float* __restrict__ bias,
                                                 float* __restrict__ h, int N) {
    int v = (blockIdx.x * 256 + threadIdx.x) >> 6;
    int f = threadIdx.x & 63;
    if (v >= N) return;
    int c = cnt[v]; if (c > CAP) c = CAP;
    int base = v * CAP;
    float dv = dinv[v];
    int sl = 0; float wl = 0.f;
    if (f < c) { sl = csr_src[base + f]; wl = dinv[sl] * dv; }
    float acc = 0.f;
    int j = 0;
    for (; j + 4 <= c; j += 4) {
        int s0 = __shfl(sl, j), s1 = __shfl(sl, j + 1);
        int s2 = __shfl(sl, j + 2), s3 = __shfl(sl, j + 3);
        float w0 = __shfl(wl, j), w1 = __shfl(wl, j + 1);
        float w2 = __shfl(wl, j + 2), w3 = __shfl(wl, j + 3);
        float x0 = bf2f(xw[(size_t)s0 * 64 + f]);
        float x1 = bf2f(xw[(size_t)s1 * 64 + f]);
        float x2 = bf2f(xw[(size_t)s2 * 64 + f]);
        float x3 = bf2f(xw[(size_t)s3 * 64 + f]);
        acc = fmaf(x0, w0, acc);
        acc = fmaf(x1, w1, acc);
        acc = fmaf(x2, w2, acc);
        acc = fmaf(x3, w3, acc);
    }
    for (; j < c; j++) {
        int s = __shfl(sl, j);
        float w = __shfl(wl, j);
        acc = fmaf(bf2f(xw[(size_t)s * 64 + f]), w, acc);
    }
    acc = fmaf(bf2f(xw[(size_t)v * 64 + f]), dv * dv, acc);
    acc += bias[f];
    h[(size_t)v * 64 + f] = fmaxf(acc, 0.f);
}

// ---------------- layer-2 aggregation fused with log_softmax, F=47 (stride 48) ----------------

__global__ __launch_bounds__(256) void agg2_lsm(const u16* __restrict__ hw,
                                                const int* __restrict__ csr_src,
                                                const int* __restrict__ cnt,
                                                const float* __restrict__ dinv,
                                                const float* __restrict__ bias,
                                                float* __restrict__ out, int N) {
    int v = (blockIdx.x * 256 + threadIdx.x) >> 6;
    int f = threadIdx.x & 63;
    if (v >= N) return;
    int c = cnt[v]; if (c > CAP) c = CAP;
    int base = v * CAP;
    float dv = dinv[v];
    int sl = 0; float wl = 0.f;
    if (f < c) { sl = csr_src[base + f]; wl = dinv[sl] * dv; }
    const bool act = (f < 47);
    float acc = 0.f;
    int j = 0;
    for (; j + 4 <= c; j += 4) {
        int s0 = __shfl(sl, j), s1 = __shfl(sl, j + 1);
        int s2 = __shfl(sl, j + 2), s3 = __shfl(sl, j + 3);
        float w0 = __shfl(wl, j), w1 = __shfl(wl, j + 1);
        float w2 = __shfl(wl, j + 2), w3 = __shfl(wl, j + 3);
        if (act) {
            float x0 = bf2f(hw[(size_t)s0 * 48 + f]);
            float x1 = bf2f(hw[(size_t)s1 * 48 + f]);
            float x2 = bf2f(hw[(size_t)s2 * 48 + f]);
            float x3 = bf2f(hw[(size_t)s3 * 48 + f]);
            acc = fmaf(x0, w0, acc);
            acc = fmaf(x1, w1, acc);
            acc = fmaf(x2, w2, acc);
            acc = fmaf(x3, w3, acc);
        }
    }
    for (; j < c; j++) {
        int s = __shfl(sl, j);
        float w = __shfl(wl, j);
        if (act) acc = fmaf(bf2f(hw[(size_t)s * 48 + f]), w, acc);
    }
    float val;
    if (act) {
        acc = fmaf(bf2f(hw[(size_t)v * 48 + f]), dv * dv, acc);
        acc += bias[f];
        val = acc;
    } else {
        val = -INFINITY;
    }
    float m = val;
    #pragma unroll
    for (int mask = 1; mask < 64; mask <<= 1)
        m = fmaxf(m, __shfl_xor(m, mask));
    float e = act ? __expf(val - m) : 0.f;
    float ssum = e;
    #pragma unroll
    for (int mask = 1; mask < 64; mask <<= 1)
        ssum += __shfl_xor(ssum, mask);
    if (act) out[(size_t)v * 47 + f] = val - m - __logf(ssum);
}

// ---------------- launch ----------------

extern "C" void kernel_launch(void* const* d_in, const int* in_sizes, int n_in,
                              void* d_out, int out_size, void* d_ws, size_t ws_size,
                              hipStream_t stream) {
    const float* x  = (const float*)d_in[0];
    const int*   ei = (const int*)d_in[1];
    const float* W1 = (const float*)d_in[2];
    const float* b1 = (const float*)d_in[3];
    const float* W2 = (const float*)d_in[4];
    const float* b2 = (const float*)d_in[5];
    float* out = (float*)d_out;

    const int N = in_sizes[0] / 128;
    const int E = in_sizes[1] / 2;
    const int* src = ei;
    const int* dst = ei + E;

    char* ws = (char*)d_ws;
    size_t off = 0;
    auto alloc = [&](size_t bytes) {
        void* p = ws + off;
        off += (bytes + 255) & ~(size_t)255;
        return p;
    };
    int*   cnt     = (int*)  alloc((size_t)N * 4);
    float* dinv    = (float*)alloc((size_t)N * 4);
    int*   csr_src = (int*)  alloc((size_t)N * CAP * 4);
    u16*   xw1     = (u16*)  alloc((size_t)N * 64 * 2);   // bf16 [N,64]
    float* hbuf    = (float*)alloc((size_t)N * 64 * 4);   // fp32 [N,64]
    u16*   hw2     = (u16*)  alloc((size_t)N * 48 * 2);   // bf16 [N,48] (47 used)

    const int chunk = (N + 7) / 8;

    hipMemsetAsync(cnt, 0, (size_t)N * 4, stream);
    build_csr<<<1024, 256, 0, stream>>>(src, dst, cnt, csr_src, E, chunk);
    compute_dinv<<<(N + 255) / 256, 256, 0, stream>>>(cnt, dinv, N);

    gemm_tiled<128, 64, 64><<<(N + 63) / 64, 256, 0, stream>>>(x, W1, xw1, N);
    agg1_relu<<<(N + 3) / 4, 256, 0, stream>>>(xw1, csr_src, cnt, dinv, b1, hbuf, N);
    gemm_tiled<64, 47, 48><<<(N + 63) / 64, 256, 0, stream>>>(hbuf, W2, hw2, N);
    agg2_lsm<<<(N + 3) / 4, 256, 0, stream>>>(hw2, csr_src, cnt, dinv, b2, out, N);
}